// Round 3
// baseline (276.809 us; speedup 1.0000x reference)
//
#include <hip/hip_runtime.h>
#include <math.h>

#define B_TOTAL   16384
#define N_DENSE   13
#define N_TABLES  26
#define V_ROWS    1000000
#define SPLIT     8          // lanes cooperating on one row

__global__ __launch_bounds__(256) void dlrm_fused_kernel(
    const float* __restrict__ x_dense,   // [B,13]
    const int*   __restrict__ x_cat,     // [B,26]
    const float* __restrict__ emb,       // [26,1000000,2]
    const float* __restrict__ bw1,       // [13,3]
    const float* __restrict__ bb1,       // [3]
    const float* __restrict__ bw2,       // [3,2]
    const float* __restrict__ bb2,       // [2]
    const float* __restrict__ tw1,       // [54,4]
    const float* __restrict__ tb1,       // [4]
    const float* __restrict__ tw2,       // [4,2]
    const float* __restrict__ tb2,       // [2]
    const float* __restrict__ tw3,       // [2,1]
    const float* __restrict__ tb3,       // [1]
    float*       __restrict__ out)       // [B,1]
{
    const int gid = blockIdx.x * blockDim.x + threadIdx.x;
    const int b   = gid >> 3;        // row handled by this 8-lane group
    const int sub = gid & (SPLIT - 1);
    if (b >= B_TOTAL) return;

    const int cbase = b * N_TABLES;

    // ---- this lane's tables: t = sub + 8k.  k=0..2 always valid; k=3 only sub<2 ----
    // Load indices first (independent), then gathers (independent), then FMAs.
    int idx0 = x_cat[cbase + sub];
    int idx1 = x_cat[cbase + sub + 8];
    int idx2 = x_cat[cbase + sub + 16];
    int idx3 = 0;
    const bool has3 = (sub + 24) < N_TABLES;   // sub 0,1 only
    if (has3) idx3 = x_cat[cbase + sub + 24];

    const float2 e0 = *reinterpret_cast<const float2*>(
        emb + ((size_t)(sub)      * V_ROWS + (size_t)idx0) * 2);
    const float2 e1 = *reinterpret_cast<const float2*>(
        emb + ((size_t)(sub + 8)  * V_ROWS + (size_t)idx1) * 2);
    const float2 e2 = *reinterpret_cast<const float2*>(
        emb + ((size_t)(sub + 16) * V_ROWS + (size_t)idx2) * 2);
    float2 e3 = make_float2(0.0f, 0.0f);
    if (has3) e3 = *reinterpret_cast<const float2*>(
        emb + ((size_t)(sub + 24) * V_ROWS + (size_t)idx3) * 2);

    // ---- partial top-layer-1 pre-activation from this lane's embeddings ----
    // input slot of table t is (2 + 2t); tw1 row-major [54,4]
    float acc[4];
    #pragma unroll
    for (int j = 0; j < 4; ++j) {
        float a = 0.0f;
        a = fmaf(e0.x, tw1[(2 + 2 * sub)          * 4 + j], a);
        a = fmaf(e0.y, tw1[(3 + 2 * sub)          * 4 + j], a);
        a = fmaf(e1.x, tw1[(2 + 2 * (sub + 8))    * 4 + j], a);
        a = fmaf(e1.y, tw1[(3 + 2 * (sub + 8))    * 4 + j], a);
        a = fmaf(e2.x, tw1[(2 + 2 * (sub + 16))   * 4 + j], a);
        a = fmaf(e2.y, tw1[(3 + 2 * (sub + 16))   * 4 + j], a);
        if (has3) {
            a = fmaf(e3.x, tw1[(2 + 2 * (sub + 24)) * 4 + j], a);
            a = fmaf(e3.y, tw1[(3 + 2 * (sub + 24)) * 4 + j], a);
        }
        acc[j] = a;
    }

    // ---- reduce partials across the 8-lane group (all lanes get the sum) ----
    #pragma unroll
    for (int j = 0; j < 4; ++j) {
        acc[j] += __shfl_xor(acc[j], 1);
        acc[j] += __shfl_xor(acc[j], 2);
        acc[j] += __shfl_xor(acc[j], 4);
    }

    // ---- bottom MLP 13 -> 3 -> 2 (computed redundantly on all 8 lanes) ----
    float xd[N_DENSE];
    {
        const int dbase = b * N_DENSE;
        #pragma unroll
        for (int i = 0; i < N_DENSE; ++i) xd[i] = x_dense[dbase + i];
    }
    float d1[3];
    #pragma unroll
    for (int j = 0; j < 3; ++j) {
        float a = bb1[j];
        #pragma unroll
        for (int i = 0; i < N_DENSE; ++i) a = fmaf(xd[i], bw1[i * 3 + j], a);
        d1[j] = fmaxf(a, 0.0f);
    }
    float d2[2];
    #pragma unroll
    for (int j = 0; j < 2; ++j) {
        float a = bb2[j];
        #pragma unroll
        for (int i = 0; i < 3; ++i) a = fmaf(d1[i], bw2[i * 2 + j], a);
        d2[j] = fmaxf(a, 0.0f);
    }

    // ---- finish top MLP ----
    float h1[4];
    #pragma unroll
    for (int j = 0; j < 4; ++j) {
        float a = acc[j] + tb1[j];
        a = fmaf(d2[0], tw1[0 * 4 + j], a);
        a = fmaf(d2[1], tw1[1 * 4 + j], a);
        h1[j] = fmaxf(a, 0.0f);
    }
    float h2[2];
    #pragma unroll
    for (int j = 0; j < 2; ++j) {
        float a = tb2[j];
        #pragma unroll
        for (int i = 0; i < 4; ++i) a = fmaf(h1[i], tw2[i * 2 + j], a);
        h2[j] = fmaxf(a, 0.0f);
    }
    float z = tb3[0];
    z = fmaf(h2[0], tw3[0], z);
    z = fmaf(h2[1], tw3[1], z);

    if (sub == 0) out[b] = 1.0f / (1.0f + expf(-z));
}

extern "C" void kernel_launch(void* const* d_in, const int* in_sizes, int n_in,
                              void* d_out, int out_size, void* d_ws, size_t ws_size,
                              hipStream_t stream) {
    const float* x_dense = (const float*)d_in[0];
    const int*   x_cat   = (const int*)  d_in[1];
    const float* emb     = (const float*)d_in[2];
    const float* bw1     = (const float*)d_in[3];
    const float* bb1     = (const float*)d_in[4];
    const float* bw2     = (const float*)d_in[5];
    const float* bb2     = (const float*)d_in[6];
    const float* tw1     = (const float*)d_in[7];
    const float* tb1     = (const float*)d_in[8];
    const float* tw2     = (const float*)d_in[9];
    const float* tb2     = (const float*)d_in[10];
    const float* tw3     = (const float*)d_in[11];
    const float* tb3     = (const float*)d_in[12];
    float* out = (float*)d_out;

    const int threads = B_TOTAL * SPLIT;       // 131072 -> 512 blocks -> 2 blocks/CU, 8 waves/CU
    const int block   = 256;
    const int grid    = threads / block;
    dlrm_fused_kernel<<<grid, block, 0, stream>>>(
        x_dense, x_cat, emb, bw1, bb1, bw2, bb2,
        tw1, tb1, tw2, tb2, tw3, tb3, out);
}